// Round 5
// baseline (153.146 us; speedup 1.0000x reference)
//
#include <hip/hip_runtime.h>
#include <hip/hip_bf16.h>

// B=8, T1=128, T2=256, C=256, H=8, hd=32, E=32, A1=16, NTYPE=3. fp32 in HBM.
// Round 5: one-shot bf16 conversion + weight transpose (prep), then all GEMMs
// and attention read MFMA fragments DIRECTLY from global (L2-resident) —
// no LDS staging, no barriers, no per-tile conversions. Masks bit-packed.
#define NC 256
#define HD 32

typedef __attribute__((ext_vector_type(8))) short short8;
typedef __attribute__((ext_vector_type(4))) short short4v;
typedef __attribute__((ext_vector_type(4))) float f32x4;

__device__ __forceinline__ unsigned short f2bf(float f) {
    union { float f; unsigned u; } v; v.f = f;
    unsigned r = v.u + 0x7fffu + ((v.u >> 16) & 1u);   // RNE
    return (unsigned short)(r >> 16);
}
__device__ __forceinline__ short8 cvt8(float4 a, float4 b) {
    short8 s;
    s[0] = (short)f2bf(a.x); s[1] = (short)f2bf(a.y);
    s[2] = (short)f2bf(a.z); s[3] = (short)f2bf(a.w);
    s[4] = (short)f2bf(b.x); s[5] = (short)f2bf(b.y);
    s[6] = (short)f2bf(b.z); s[7] = (short)f2bf(b.w);
    return s;
}

// ---------------------------------------------------------------------------
// prep: bf16 conversions, weight transposes (W[k][n] -> WT[n][k]), zero-pad,
// mask bit-packing. Block regions:
//  0..63   x1b    64..95 A2(=x2|ax2|0)   96..99 ax1p
//  100..111 WqT   112..123 WkT   124..135 WvT   136..138 WvA1T   139..150 WpT
//  151..198 mask bits (ballot)
// ---------------------------------------------------------------------------
__global__ __launch_bounds__(256) void prep(
    const float* __restrict__ x1, const float* __restrict__ x2,
    const float* __restrict__ ax1, const float* __restrict__ ax2,
    const float* __restrict__ Wq, const float* __restrict__ Wk,
    const float* __restrict__ Wv, const float* __restrict__ Wp,
    const int* __restrict__ masks,
    short* __restrict__ x1b, short* __restrict__ A2, short* __restrict__ ax1p,
    short* __restrict__ WqT, short* __restrict__ WkT, short* __restrict__ WvT,
    short* __restrict__ WvA1T, short* __restrict__ WpT,
    unsigned int* __restrict__ mb)
{
    const int bx = blockIdx.x, tid = threadIdx.x;
    const short8 zero8 = {0, 0, 0, 0, 0, 0, 0, 0};

    if (bx < 64) {                                  // x1 -> x1b (flat)
        const size_t base = ((size_t)bx * 256 + tid) * 16;
        const float* p = x1 + base;
        float4 a = *(const float4*)p,       b = *(const float4*)(p + 4);
        float4 c = *(const float4*)(p + 8), d = *(const float4*)(p + 12);
        *(short8*)&x1b[base]     = cvt8(a, b);
        *(short8*)&x1b[base + 8] = cvt8(c, d);
    } else if (bx < 96) {                           // A2 = [x2 | ax2 | 0]
        const int r0 = (bx - 64) * 64;
        for (int rr = 0; rr < 64; ++rr) {
            const int row = r0 + rr;
            A2[row * 288 + tid] = (short)f2bf(x2[(size_t)row * 256 + tid]);
            if (tid < 16)
                A2[row * 288 + 256 + tid] = (short)f2bf(ax2[row * 16 + tid]);
            else if (tid < 32)
                A2[row * 288 + 256 + tid] = 0;
        }
    } else if (bx < 100) {                          // ax1p = [ax1 | 0]
        const int row = (bx - 96) * 256 + tid;
        const float* p = ax1 + (size_t)row * 16;
        float4 a = *(const float4*)p,       b = *(const float4*)(p + 4);
        float4 c = *(const float4*)(p + 8), d = *(const float4*)(p + 12);
        short* o = ax1p + (size_t)row * 32;
        *(short8*)o        = cvt8(a, b);
        *(short8*)(o + 8)  = cvt8(c, d);
        *(short8*)(o + 16) = zero8;
        *(short8*)(o + 24) = zero8;
    } else if (bx < 112) {                          // WqT: 3 types x 4 blocks
        const int idx = bx - 100, i = idx >> 2, o0 = (idx & 3) * 8;
        const float* W = Wq + (size_t)i * 256 * 256;
        short* O = WqT + (size_t)i * 256 * 256;
        for (int o = o0; o < o0 + 8; ++o) {
            short8 s;
#pragma unroll
            for (int j = 0; j < 8; ++j) s[j] = (short)f2bf(W[(size_t)(o * 8 + j) * 256 + tid]);
            *(short8*)&O[(size_t)tid * 256 + o * 8] = s;
        }
    } else if (bx < 136) {                          // WkT / WvT (K'=288, remapped)
        const int idx = bx - 112, kv = idx / 12, sub = idx % 12;
        const int i = sub >> 2, o0 = (sub & 3) * 9;
        const float* W = (kv ? Wv : Wk) + (size_t)i * 288 * 256;
        short* O = (kv ? WvT : WkT) + (size_t)i * 256 * 288;
        for (int o = o0; o < o0 + 9; ++o) {
            short8 s;
#pragma unroll
            for (int j = 0; j < 8; ++j) {
                const int kp = o * 8 + j;
                const int src = (kp < 256) ? kp : (kp < 272 ? kp + 16 : -1);
                s[j] = (src >= 0) ? (short)f2bf(W[(size_t)src * 256 + tid]) : (short)0;
            }
            *(short8*)&O[(size_t)tid * 288 + o * 8] = s;
        }
    } else if (bx < 139) {                          // WvA1T (Wv rows 256..271)
        const int i = bx - 136;
        const float* W = Wv + (size_t)i * 288 * 256;
        short* O = WvA1T + (size_t)i * 256 * 32;
        short8 s0, s1;
#pragma unroll
        for (int j = 0; j < 8; ++j) {
            s0[j] = (short)f2bf(W[(size_t)(256 + j) * 256 + tid]);
            s1[j] = (short)f2bf(W[(size_t)(264 + j) * 256 + tid]);
        }
        short* o = O + (size_t)tid * 32;
        *(short8*)o = s0; *(short8*)(o + 8) = s1;
        *(short8*)(o + 16) = zero8; *(short8*)(o + 24) = zero8;
    } else if (bx < 151) {                          // WpT
        const int idx = bx - 139, i = idx >> 2, o0 = (idx & 3) * 8;
        const float* W = Wp + (size_t)i * 256 * 256;
        short* O = WpT + (size_t)i * 256 * 256;
        for (int o = o0; o < o0 + 8; ++o) {
            short8 s;
#pragma unroll
            for (int j = 0; j < 8; ++j) s[j] = (short)f2bf(W[(size_t)(o * 8 + j) * 256 + tid]);
            *(short8*)&O[(size_t)tid * 256 + o * 8] = s;
        }
    } else {                                        // mask bits (ballot)
        const int r0 = (bx - 151) * 64;
        const int wave = tid >> 6, lane = tid & 63;
        for (int rr = 0; rr < 64; ++rr) {
            const int row = r0 + rr;
            const int mk = masks[(size_t)row * 256 + tid];
            unsigned long long bal = __ballot(mk != 0);
            if (lane == 0) {
                mb[row * 8 + wave * 2 + 0] = (unsigned int)bal;
                mb[row * 8 + wave * 2 + 1] = (unsigned int)(bal >> 32);
            }
        }
    }
}

// ---------------------------------------------------------------------------
// fused_gemm: all linear layers, frags direct from global bf16. No LDS.
//  blocks 0..47    q  = x1b @ WqT + bq      -> q_bf [i][1024][256]
//  blocks 48..143  kb = A2 @ WkT + bk       -> kb_bf [i][2048][256]
//  blocks 144..239 vb = A2 @ WvT + bv       -> vbT  [i][256][2048] (transposed!)
//  blocks 240..287 va = ax1p @ WvA1T        -> va fp32 [i][1024][256]
// 128x128 tile, 4 waves, wave = 64x64 (4x4 16-tiles).
// ---------------------------------------------------------------------------
__global__ __launch_bounds__(256) void fused_gemm(
    const short* __restrict__ x1b, const short* __restrict__ A2,
    const short* __restrict__ ax1p,
    const short* __restrict__ WqT, const short* __restrict__ WkT,
    const short* __restrict__ WvT, const short* __restrict__ WvA1T,
    const float* __restrict__ bq, const float* __restrict__ bk,
    const float* __restrict__ bv,
    short* __restrict__ qb, short* __restrict__ kbb,
    short* __restrict__ vbT, float* __restrict__ va)
{
    const int bx = blockIdx.x;
    const short *Ab, *Wb;
    const float* bias = nullptr;
    short* outb = nullptr; float* outf = nullptr;
    int LDA, LDW, nsteps, mode, m0, n0;   // mode: 0 bf16, 1 bf16-transposed, 2 f32
    if (bx < 48) {
        const int i = bx >> 4, t = bx & 15;
        m0 = (t >> 1) * 128; n0 = (t & 1) * 128;
        Ab = x1b; LDA = 256; Wb = WqT + (size_t)i * 256 * 256; LDW = 256;
        nsteps = 8; bias = bq + i * 256; outb = qb + (size_t)i * 1024 * 256; mode = 0;
    } else if (bx < 144) {
        const int idx = bx - 48, i = idx >> 5, t = idx & 31;
        m0 = (t >> 1) * 128; n0 = (t & 1) * 128;
        Ab = A2; LDA = 288; Wb = WkT + (size_t)i * 256 * 288; LDW = 288;
        nsteps = 9; bias = bk + i * 256; outb = kbb + (size_t)i * 2048 * 256; mode = 0;
    } else if (bx < 240) {
        const int idx = bx - 144, i = idx >> 5, t = idx & 31;
        m0 = (t >> 1) * 128; n0 = (t & 1) * 128;
        Ab = A2; LDA = 288; Wb = WvT + (size_t)i * 256 * 288; LDW = 288;
        nsteps = 9; bias = bv + i * 256; outb = vbT + (size_t)i * 256 * 2048; mode = 1;
    } else {
        const int idx = bx - 240, i = idx >> 4, t = idx & 15;
        m0 = (t >> 1) * 128; n0 = (t & 1) * 128;
        Ab = ax1p; LDA = 32; Wb = WvA1T + (size_t)i * 256 * 32; LDW = 32;
        nsteps = 1; outf = va + (size_t)i * 1024 * 256; mode = 2;
    }

    const int tid = threadIdx.x;
    const int wave = tid >> 6, lane = tid & 63;
    const int wy = wave >> 1, wx = wave & 1;
    const int qd = lane >> 4, ml = lane & 15;

    f32x4 acc[4][4];
#pragma unroll
    for (int a = 0; a < 4; ++a)
#pragma unroll
        for (int b = 0; b < 4; ++b) acc[a][b] = {0.f, 0.f, 0.f, 0.f};

    for (int step = 0; step < nsteps; ++step) {
        short8 af[4], bf[4];
#pragma unroll
        for (int mt = 0; mt < 4; ++mt)
            af[mt] = *(const short8*)&Ab[(size_t)(m0 + wy * 64 + mt * 16 + ml) * LDA + step * 32 + qd * 8];
#pragma unroll
        for (int nt = 0; nt < 4; ++nt)
            bf[nt] = *(const short8*)&Wb[(size_t)(n0 + wx * 64 + nt * 16 + ml) * LDW + step * 32 + qd * 8];
#pragma unroll
        for (int mt = 0; mt < 4; ++mt)
#pragma unroll
            for (int nt = 0; nt < 4; ++nt)
                acc[mt][nt] = __builtin_amdgcn_mfma_f32_16x16x32_bf16(
                    af[mt], bf[nt], acc[mt][nt], 0, 0, 0);
    }

#pragma unroll
    for (int nt = 0; nt < 4; ++nt) {
        const int col = n0 + wx * 64 + nt * 16 + ml;
        const float bsv = bias ? bias[col] : 0.f;
#pragma unroll
        for (int mt = 0; mt < 4; ++mt) {
            const int row0 = m0 + wy * 64 + mt * 16 + qd * 4;
            if (mode == 0) {
#pragma unroll
                for (int r = 0; r < 4; ++r)
                    outb[(size_t)(row0 + r) * 256 + col] = (short)f2bf(acc[mt][nt][r] + bsv);
            } else if (mode == 1) {
                short4v s;
                s.x = (short)f2bf(acc[mt][nt][0] + bsv);
                s.y = (short)f2bf(acc[mt][nt][1] + bsv);
                s.z = (short)f2bf(acc[mt][nt][2] + bsv);
                s.w = (short)f2bf(acc[mt][nt][3] + bsv);
                *(short4v*)&outb[(size_t)col * 2048 + row0] = s;
            } else {
#pragma unroll
                for (int r = 0; r < 4; ++r)
                    outf[(size_t)(row0 + r) * 256 + col] = acc[mt][nt][r];
            }
        }
    }
}

// ---------------------------------------------------------------------------
// attn: grid 384 = (i, b, h, tc). 4 waves; wave = 16 t-rows x 256 s.
// ZERO barriers: Q/K frags direct from global bf16; P -> per-wave LDS panels;
// V frags direct from pre-transposed vbT. Masks from packed bits.
// No-max-shift softmax (verified r4); all-masked row -> uniform 1/256.
// y written bf16 (+ va fp32) for proj.
// ---------------------------------------------------------------------------
__global__ __launch_bounds__(256) void attn_mfma(
    const short* __restrict__ qb, const short* __restrict__ kbb,
    const short* __restrict__ vbT, const float* __restrict__ va,
    const unsigned int* __restrict__ mb, short* __restrict__ yb)
{
    const int bx = blockIdx.x;
    const int tc = bx & 1, h = (bx >> 1) & 7, b = (bx >> 4) & 7, i = bx >> 7;
    const size_t bb = (size_t)i * 8 + b;

    __shared__ short Ps[4][32 * 16 * 8];   // per-wave A-panels, 8 KB each

    const int tid = threadIdx.x;
    const int wave = tid >> 6, lane = tid & 63;
    const int ml = lane & 15, qd = lane >> 4;

    // Q A-frag, pre-scaled by 1/sqrt(hd)*log2(e) (bf16 -> f32 -> scale -> bf16)
    const float qscale = 0.17677669529663687f * 1.4426950408889634f;
    short8 af;
    {
        const int t = tc * 64 + wave * 16 + ml;
        short8 qr = *(const short8*)&qb[(bb * 128 + t) * 256 + h * HD + qd * 8];
#pragma unroll
        for (int j = 0; j < 8; ++j) {
            union { float f; unsigned u; } v;
            v.u = ((unsigned)(unsigned short)qr[j]) << 16;
            af[j] = (short)f2bf(v.f * qscale);
        }
    }

    // QK^T: B-frags direct from kb_bf
    f32x4 sacc[16];
#pragma unroll
    for (int nt = 0; nt < 16; ++nt) sacc[nt] = {0.f, 0.f, 0.f, 0.f};
#pragma unroll
    for (int nt = 0; nt < 16; ++nt) {
        short8 bf = *(const short8*)&kbb[(bb * 256 + nt * 16 + ml) * 256 + h * HD + qd * 8];
        sacc[nt] = __builtin_amdgcn_mfma_f32_16x16x32_bf16(af, bf, sacc[nt], 0, 0, 0);
    }

    // mask bits: row tb+r -> 8 u32 words; bit for col=16nt+ml is
    // word nt>>1, bit (nt&1)*16+ml.
    const int tb = tc * 64 + wave * 16 + qd * 4;
    uint4 wlo[4], whi[4];
#pragma unroll
    for (int r = 0; r < 4; ++r) {
        const unsigned int* p = mb + (bb * 128 + tb + r) * 8;
        wlo[r] = *(const uint4*)p;
        whi[r] = *(const uint4*)(p + 4);
    }

    f32x4 rs = {0.f, 0.f, 0.f, 0.f};
#pragma unroll
    for (int nt = 0; nt < 16; ++nt) {
#pragma unroll
        for (int r = 0; r < 4; ++r) {
            unsigned int w;
            switch (nt >> 1) {
                case 0: w = wlo[r].x; break; case 1: w = wlo[r].y; break;
                case 2: w = wlo[r].z; break; case 3: w = wlo[r].w; break;
                case 4: w = whi[r].x; break; case 5: w = whi[r].y; break;
                case 6: w = whi[r].z; break; default: w = whi[r].w; break;
            }
            const bool mk = (w >> ((nt & 1) * 16 + ml)) & 1u;
            float e = mk ? __builtin_amdgcn_exp2f(sacc[nt][r]) : 0.f;
            sacc[nt][r] = e;
            rs[r] += e;
        }
    }
#pragma unroll
    for (int off = 1; off <= 8; off <<= 1) {
#pragma unroll
        for (int r = 0; r < 4; ++r) rs[r] += __shfl_xor(rs[r], off);
    }
    f32x4 pinv, pfill;
#pragma unroll
    for (int r = 0; r < 4; ++r) {
        const bool z = (rs[r] == 0.f);
        pinv[r]  = z ? 0.f : 1.f / rs[r];
        pfill[r] = z ? (1.f / 256.f) : 0.f;
    }

    // P -> this wave's private LDS A-panels (same-wave dep, no barrier)
    short* Pw = &Ps[wave][0];
#pragma unroll
    for (int nt = 0; nt < 16; ++nt) {
        const int sgrp = 2 * nt + (ml >> 3);
        const int pos = ml & 7;
#pragma unroll
        for (int r = 0; r < 4; ++r) {
            const float p = sacc[nt][r] * pinv[r] + pfill[r];
            Pw[(sgrp * 16 + qd * 4 + r) * 8 + pos] = (short)f2bf(p);
        }
    }

    // PV: V B-frags direct from vbT [i][d][2048]
    f32x4 oacc[2];
    oacc[0] = {0.f, 0.f, 0.f, 0.f};
    oacc[1] = {0.f, 0.f, 0.f, 0.f};
    const short* Vb = vbT + (size_t)i * 256 * 2048 + (size_t)b * 256;
#pragma unroll
    for (int ks = 0; ks < 8; ++ks) {
        short8 pa = *(const short8*)&Pw[((ks * 4 + qd) * 16 + ml) * 8];
#pragma unroll
        for (int n2 = 0; n2 < 2; ++n2) {
            short8 vf = *(const short8*)&Vb[(size_t)(h * HD + n2 * 16 + ml) * 2048 + ks * 32 + qd * 8];
            oacc[n2] = __builtin_amdgcn_mfma_f32_16x16x32_bf16(pa, vf, oacc[n2], 0, 0, 0);
        }
    }

    // epilogue: y = O + vaux (bf16 out; sum(p)=1 absorbs vaux)
#pragma unroll
    for (int n2 = 0; n2 < 2; ++n2) {
        const int d = h * HD + n2 * 16 + ml;
#pragma unroll
        for (int r = 0; r < 4; ++r) {
            const size_t idx = (bb * 128 + tb + r) * 256 + d;
            yb[idx] = (short)f2bf(oacc[n2][r] + va[idx]);
        }
    }
}

// ---------------------------------------------------------------------------
// proj: out = sum_i y[i] @ Wp[i] + sum_i bp[i], fp32 out. Frags from global.
// grid 64 (16 m x 4 n, 64x64 tiles); wave = 32x32. No LDS/barriers.
// ---------------------------------------------------------------------------
__global__ __launch_bounds__(256) void proj2(
    const short* __restrict__ yb, const short* __restrict__ WpT,
    const float* __restrict__ bp, float* __restrict__ out)
{
    const int bx = blockIdx.x;
    const int m0 = (bx >> 2) * 64, n0 = (bx & 3) * 64;
    const int tid = threadIdx.x;
    const int wave = tid >> 6, lane = tid & 63;
    const int wy = wave >> 1, wx = wave & 1;
    const int qd = lane >> 4, ml = lane & 15;

    f32x4 acc[2][2];
#pragma unroll
    for (int a = 0; a < 2; ++a)
#pragma unroll
        for (int b = 0; b < 2; ++b) acc[a][b] = {0.f, 0.f, 0.f, 0.f};

    for (int i = 0; i < 3; ++i) {
        const short* A = yb + (size_t)i * 1024 * 256;
        const short* W = WpT + (size_t)i * 256 * 256;
#pragma unroll
        for (int step = 0; step < 8; ++step) {
            short8 af[2], bf[2];
#pragma unroll
            for (int mt = 0; mt < 2; ++mt)
                af[mt] = *(const short8*)&A[(size_t)(m0 + wy * 32 + mt * 16 + ml) * 256 + step * 32 + qd * 8];
#pragma unroll
            for (int nt = 0; nt < 2; ++nt)
                bf[nt] = *(const short8*)&W[(size_t)(n0 + wx * 32 + nt * 16 + ml) * 256 + step * 32 + qd * 8];
#pragma unroll
            for (int mt = 0; mt < 2; ++mt)
#pragma unroll
                for (int nt = 0; nt < 2; ++nt)
                    acc[mt][nt] = __builtin_amdgcn_mfma_f32_16x16x32_bf16(
                        af[mt], bf[nt], acc[mt][nt], 0, 0, 0);
        }
    }
#pragma unroll
    for (int nt = 0; nt < 2; ++nt) {
        const int col = n0 + wx * 32 + nt * 16 + ml;
        const float b3 = bp[col] + bp[256 + col] + bp[512 + col];
#pragma unroll
        for (int mt = 0; mt < 2; ++mt) {
            const int row0 = m0 + wy * 32 + mt * 16 + qd * 4;
#pragma unroll
            for (int r = 0; r < 4; ++r)
                out[(size_t)(row0 + r) * 256 + col] = acc[mt][nt][r] + b3;
        }
    }
}

extern "C" void kernel_launch(void* const* d_in, const int* in_sizes, int n_in,
                              void* d_out, int out_size, void* d_ws, size_t ws_size,
                              hipStream_t stream)
{
    const float* x1  = (const float*)d_in[0];
    const float* x2  = (const float*)d_in[1];
    const float* ax1 = (const float*)d_in[2];
    const float* ax2 = (const float*)d_in[3];
    const int*   mk  = (const int*)d_in[4];
    const float* Wq  = (const float*)d_in[5];
    const float* bq  = (const float*)d_in[6];
    const float* Wk  = (const float*)d_in[7];
    const float* bk  = (const float*)d_in[8];
    const float* Wv  = (const float*)d_in[9];
    const float* bv  = (const float*)d_in[10];
    const float* Wp  = (const float*)d_in[11];
    const float* bp  = (const float*)d_in[12];

    char* w = (char*)d_ws;
    short* x1b   = (short*)(w + 0);              // 512 KB
    short* A2    = (short*)(w + 524288);         // 1.125 MB
    short* ax1p  = (short*)(w + 1703936);        // 64 KB
    short* WqT   = (short*)(w + 1769472);        // 384 KB
    short* WkT   = (short*)(w + 2162688);        // 432 KB
    short* WvT   = (short*)(w + 2605056);        // 432 KB
    short* WvA1T = (short*)(w + 3047424);        // 48 KB
    short* WpT   = (short*)(w + 3096576);        // 384 KB
    unsigned int* mbits = (unsigned int*)(w + 3489792);   // 96 KB
    short* qb    = (short*)(w + 3588096);        // 1.5 MB
    short* kbb   = (short*)(w + 5160960);        // 3 MB
    short* vbT   = (short*)(w + 8306688);        // 3 MB
    float* va    = (float*)(w + 11452416);       // 3 MB
    short* yb    = (short*)(w + 14598144);       // 1.5 MB

    prep<<<dim3(199), 256, 0, stream>>>(x1, x2, ax1, ax2, Wq, Wk, Wv, Wp, mk,
                                        x1b, A2, ax1p, WqT, WkT, WvT, WvA1T,
                                        WpT, mbits);
    fused_gemm<<<dim3(288), 256, 0, stream>>>(x1b, A2, ax1p, WqT, WkT, WvT,
                                              WvA1T, bq, bk, bv, qb, kbb, vbT, va);
    attn_mfma<<<dim3(384), 256, 0, stream>>>(qb, kbb, vbT, va, mbits, yb);
    proj2<<<dim3(64), 256, 0, stream>>>(yb, WpT, bp, (float*)d_out);
}

// Round 6
// 130.761 us; speedup vs baseline: 1.1712x; 1.1712x over previous
//
#include <hip/hip_runtime.h>
#include <hip/hip_bf16.h>

// B=8, T1=128, T2=256, C=256, H=8, hd=32, E=32, A1=16, NTYPE=3. fp32 in HBM.
// Round 6: prep rewritten for coalescing (r5's prep was 50us: column-strided
// transpose reads + serial scalar-store A2 loop). GEMM/attn/proj unchanged
// from r5 (verified absmax 9.77e-4, all below 43us fill floor).
#define NC 256
#define HD 32

typedef __attribute__((ext_vector_type(8))) short short8;
typedef __attribute__((ext_vector_type(4))) short short4v;
typedef __attribute__((ext_vector_type(4))) float f32x4;

__device__ __forceinline__ unsigned short f2bf(float f) {
    union { float f; unsigned u; } v; v.f = f;
    unsigned r = v.u + 0x7fffu + ((v.u >> 16) & 1u);   // RNE
    return (unsigned short)(r >> 16);
}
__device__ __forceinline__ short8 cvt8(float4 a, float4 b) {
    short8 s;
    s[0] = (short)f2bf(a.x); s[1] = (short)f2bf(a.y);
    s[2] = (short)f2bf(a.z); s[3] = (short)f2bf(a.w);
    s[4] = (short)f2bf(b.x); s[5] = (short)f2bf(b.y);
    s[6] = (short)f2bf(b.z); s[7] = (short)f2bf(b.w);
    return s;
}

// ---------------------------------------------------------------------------
// prep_a: activations + masks, fully coalesced.
//  0..63    x1b                      64..351  A2 = [x2|ax2|0] (thread=(row,col8))
//  352..355 ax1p                     356..547 mask bit-pack (16 rows/block)
// ---------------------------------------------------------------------------
__global__ __launch_bounds__(256) void prep_a(
    const float* __restrict__ x1, const float* __restrict__ x2,
    const float* __restrict__ ax1, const float* __restrict__ ax2,
    const int* __restrict__ masks,
    short* __restrict__ x1b, short* __restrict__ A2, short* __restrict__ ax1p,
    unsigned int* __restrict__ mb)
{
    const int bx = blockIdx.x, tid = threadIdx.x;
    const short8 zero8 = {0, 0, 0, 0, 0, 0, 0, 0};

    if (bx < 64) {                                  // x1 -> x1b
        const size_t base = ((size_t)bx * 256 + tid) * 16;
        const float* p = x1 + base;
        float4 a = *(const float4*)p,       b = *(const float4*)(p + 4);
        float4 c = *(const float4*)(p + 8), d = *(const float4*)(p + 12);
        *(short8*)&x1b[base]     = cvt8(a, b);
        *(short8*)&x1b[base + 8] = cvt8(c, d);
    } else if (bx < 352) {                          // A2: 2048 rows x 36 col8
        const int g = (bx - 64) * 256 + tid;        // 73728 work items
        const int row = g / 36, c8 = g - row * 36;
        short8 s;
        if (c8 < 32) {
            const float* p = x2 + (size_t)row * 256 + c8 * 8;
            s = cvt8(*(const float4*)p, *(const float4*)(p + 4));
        } else if (c8 < 34) {
            const float* p = ax2 + (size_t)row * 16 + (c8 - 32) * 8;
            s = cvt8(*(const float4*)p, *(const float4*)(p + 4));
        } else {
            s = zero8;
        }
        *(short8*)&A2[(size_t)row * 288 + c8 * 8] = s;
    } else if (bx < 356) {                          // ax1p = [ax1 | 0]
        const int row = (bx - 352) * 256 + tid;
        const float* p = ax1 + (size_t)row * 16;
        float4 a = *(const float4*)p,       b = *(const float4*)(p + 4);
        float4 c = *(const float4*)(p + 8), d = *(const float4*)(p + 12);
        short* o = ax1p + (size_t)row * 32;
        *(short8*)o        = cvt8(a, b);
        *(short8*)(o + 8)  = cvt8(c, d);
        *(short8*)(o + 16) = zero8;
        *(short8*)(o + 24) = zero8;
    } else {                                        // masks: 3072 rows total
        const int r0 = (bx - 356) * 16;
        const int wave = tid >> 6, lane = tid & 63;
        for (int rr = 0; rr < 16; ++rr) {
            const int row = r0 + rr;
            const int mk = masks[(size_t)row * 256 + tid];
            unsigned long long bal = __ballot(mk != 0);
            if (lane == 0) {
                mb[row * 8 + wave * 2 + 0] = (unsigned int)bal;
                mb[row * 8 + wave * 2 + 1] = (unsigned int)(bal >> 32);
            }
        }
    }
}

// ---------------------------------------------------------------------------
// prep_w: weight transposes W[k][n] -> WT[n][k], read-coalesced.
// Thread = (k8-group from block, n = tid). For each j, the wave reads
// W[k8*8+j][n0..n0+63] = 256B contiguous. One short8 write per thread.
//  0..95 WqT (i=bx/32, k8=bx%32)    96..203 WkT (i=idx/36, k8=idx%36, remap)
//  204..311 WvT (same)              312..407 WpT    408..410 WvA1T
// ---------------------------------------------------------------------------
__global__ __launch_bounds__(256) void prep_w(
    const float* __restrict__ Wq, const float* __restrict__ Wk,
    const float* __restrict__ Wv, const float* __restrict__ Wp,
    short* __restrict__ WqT, short* __restrict__ WkT, short* __restrict__ WvT,
    short* __restrict__ WvA1T, short* __restrict__ WpT)
{
    const int bx = blockIdx.x, n = threadIdx.x;

    if (bx < 96) {                                  // WqT
        const int i = bx >> 5, k8 = bx & 31;
        const float* W = Wq + (size_t)i * 256 * 256;
        short8 s;
#pragma unroll
        for (int j = 0; j < 8; ++j) s[j] = (short)f2bf(W[(size_t)(k8 * 8 + j) * 256 + n]);
        *(short8*)&WqT[(size_t)i * 256 * 256 + (size_t)n * 256 + k8 * 8] = s;
    } else if (bx < 312) {                          // WkT / WvT, K'=288 remapped
        const int idx0 = bx - 96;
        const int kv = idx0 / 108, idx = idx0 % 108;
        const int i = idx / 36, k8 = idx % 36;
        const float* W = (kv ? Wv : Wk) + (size_t)i * 288 * 256;
        short* O = (kv ? WvT : WkT) + (size_t)i * 256 * 288;
        short8 s;
#pragma unroll
        for (int j = 0; j < 8; ++j) {
            const int kp = k8 * 8 + j;
            const int src = (kp < 256) ? kp : (kp < 272 ? kp + 16 : -1);
            s[j] = (src >= 0) ? (short)f2bf(W[(size_t)src * 256 + n]) : (short)0;
        }
        *(short8*)&O[(size_t)n * 288 + k8 * 8] = s;
    } else if (bx < 408) {                          // WpT
        const int idx = bx - 312, i = idx >> 5, k8 = idx & 31;
        const float* W = Wp + (size_t)i * 256 * 256;
        short8 s;
#pragma unroll
        for (int j = 0; j < 8; ++j) s[j] = (short)f2bf(W[(size_t)(k8 * 8 + j) * 256 + n]);
        *(short8*)&WpT[(size_t)i * 256 * 256 + (size_t)n * 256 + k8 * 8] = s;
    } else {                                        // WvA1T: Wv rows 256..271 + pad
        const int i = bx - 408;
        const float* W = Wv + (size_t)i * 288 * 256;
        short* O = WvA1T + (size_t)i * 256 * 32 + (size_t)n * 32;
#pragma unroll
        for (int k8 = 0; k8 < 4; ++k8) {
            short8 s;
#pragma unroll
            for (int j = 0; j < 8; ++j) {
                const int kp = k8 * 8 + j;
                s[j] = (kp < 16) ? (short)f2bf(W[(size_t)(256 + kp) * 256 + n]) : (short)0;
            }
            *(short8*)&O[k8 * 8] = s;
        }
    }
}

// ---------------------------------------------------------------------------
// fused_gemm (UNCHANGED from r5): frags direct from global bf16, no LDS.
// ---------------------------------------------------------------------------
__global__ __launch_bounds__(256) void fused_gemm(
    const short* __restrict__ x1b, const short* __restrict__ A2,
    const short* __restrict__ ax1p,
    const short* __restrict__ WqT, const short* __restrict__ WkT,
    const short* __restrict__ WvT, const short* __restrict__ WvA1T,
    const float* __restrict__ bq, const float* __restrict__ bk,
    const float* __restrict__ bv,
    short* __restrict__ qb, short* __restrict__ kbb,
    short* __restrict__ vbT, float* __restrict__ va)
{
    const int bx = blockIdx.x;
    const short *Ab, *Wb;
    const float* bias = nullptr;
    short* outb = nullptr; float* outf = nullptr;
    int LDA, LDW, nsteps, mode, m0, n0;
    if (bx < 48) {
        const int i = bx >> 4, t = bx & 15;
        m0 = (t >> 1) * 128; n0 = (t & 1) * 128;
        Ab = x1b; LDA = 256; Wb = WqT + (size_t)i * 256 * 256; LDW = 256;
        nsteps = 8; bias = bq + i * 256; outb = qb + (size_t)i * 1024 * 256; mode = 0;
    } else if (bx < 144) {
        const int idx = bx - 48, i = idx >> 5, t = idx & 31;
        m0 = (t >> 1) * 128; n0 = (t & 1) * 128;
        Ab = A2; LDA = 288; Wb = WkT + (size_t)i * 256 * 288; LDW = 288;
        nsteps = 9; bias = bk + i * 256; outb = kbb + (size_t)i * 2048 * 256; mode = 0;
    } else if (bx < 240) {
        const int idx = bx - 144, i = idx >> 5, t = idx & 31;
        m0 = (t >> 1) * 128; n0 = (t & 1) * 128;
        Ab = A2; LDA = 288; Wb = WvT + (size_t)i * 256 * 288; LDW = 288;
        nsteps = 9; bias = bv + i * 256; outb = vbT + (size_t)i * 256 * 2048; mode = 1;
    } else {
        const int idx = bx - 240, i = idx >> 4, t = idx & 15;
        m0 = (t >> 1) * 128; n0 = (t & 1) * 128;
        Ab = ax1p; LDA = 32; Wb = WvA1T + (size_t)i * 256 * 32; LDW = 32;
        nsteps = 1; outf = va + (size_t)i * 1024 * 256; mode = 2;
    }

    const int tid = threadIdx.x;
    const int wave = tid >> 6, lane = tid & 63;
    const int wy = wave >> 1, wx = wave & 1;
    const int qd = lane >> 4, ml = lane & 15;

    f32x4 acc[4][4];
#pragma unroll
    for (int a = 0; a < 4; ++a)
#pragma unroll
        for (int b = 0; b < 4; ++b) acc[a][b] = {0.f, 0.f, 0.f, 0.f};

    for (int step = 0; step < nsteps; ++step) {
        short8 af[4], bf[4];
#pragma unroll
        for (int mt = 0; mt < 4; ++mt)
            af[mt] = *(const short8*)&Ab[(size_t)(m0 + wy * 64 + mt * 16 + ml) * LDA + step * 32 + qd * 8];
#pragma unroll
        for (int nt = 0; nt < 4; ++nt)
            bf[nt] = *(const short8*)&Wb[(size_t)(n0 + wx * 64 + nt * 16 + ml) * LDW + step * 32 + qd * 8];
#pragma unroll
        for (int mt = 0; mt < 4; ++mt)
#pragma unroll
            for (int nt = 0; nt < 4; ++nt)
                acc[mt][nt] = __builtin_amdgcn_mfma_f32_16x16x32_bf16(
                    af[mt], bf[nt], acc[mt][nt], 0, 0, 0);
    }

#pragma unroll
    for (int nt = 0; nt < 4; ++nt) {
        const int col = n0 + wx * 64 + nt * 16 + ml;
        const float bsv = bias ? bias[col] : 0.f;
#pragma unroll
        for (int mt = 0; mt < 4; ++mt) {
            const int row0 = m0 + wy * 64 + mt * 16 + qd * 4;
            if (mode == 0) {
#pragma unroll
                for (int r = 0; r < 4; ++r)
                    outb[(size_t)(row0 + r) * 256 + col] = (short)f2bf(acc[mt][nt][r] + bsv);
            } else if (mode == 1) {
                short4v s;
                s.x = (short)f2bf(acc[mt][nt][0] + bsv);
                s.y = (short)f2bf(acc[mt][nt][1] + bsv);
                s.z = (short)f2bf(acc[mt][nt][2] + bsv);
                s.w = (short)f2bf(acc[mt][nt][3] + bsv);
                *(short4v*)&outb[(size_t)col * 2048 + row0] = s;
            } else {
#pragma unroll
                for (int r = 0; r < 4; ++r)
                    outf[(size_t)(row0 + r) * 256 + col] = acc[mt][nt][r];
            }
        }
    }
}

// ---------------------------------------------------------------------------
// attn (UNCHANGED from r5): zero barriers, direct global frags, bit-masks.
// ---------------------------------------------------------------------------
__global__ __launch_bounds__(256) void attn_mfma(
    const short* __restrict__ qb, const short* __restrict__ kbb,
    const short* __restrict__ vbT, const float* __restrict__ va,
    const unsigned int* __restrict__ mb, short* __restrict__ yb)
{
    const int bx = blockIdx.x;
    const int tc = bx & 1, h = (bx >> 1) & 7, b = (bx >> 4) & 7, i = bx >> 7;
    const size_t bb = (size_t)i * 8 + b;

    __shared__ short Ps[4][32 * 16 * 8];

    const int tid = threadIdx.x;
    const int wave = tid >> 6, lane = tid & 63;
    const int ml = lane & 15, qd = lane >> 4;

    const float qscale = 0.17677669529663687f * 1.4426950408889634f;
    short8 af;
    {
        const int t = tc * 64 + wave * 16 + ml;
        short8 qr = *(const short8*)&qb[(bb * 128 + t) * 256 + h * HD + qd * 8];
#pragma unroll
        for (int j = 0; j < 8; ++j) {
            union { float f; unsigned u; } v;
            v.u = ((unsigned)(unsigned short)qr[j]) << 16;
            af[j] = (short)f2bf(v.f * qscale);
        }
    }

    f32x4 sacc[16];
#pragma unroll
    for (int nt = 0; nt < 16; ++nt) sacc[nt] = {0.f, 0.f, 0.f, 0.f};
#pragma unroll
    for (int nt = 0; nt < 16; ++nt) {
        short8 bf = *(const short8*)&kbb[(bb * 256 + nt * 16 + ml) * 256 + h * HD + qd * 8];
        sacc[nt] = __builtin_amdgcn_mfma_f32_16x16x32_bf16(af, bf, sacc[nt], 0, 0, 0);
    }

    const int tb = tc * 64 + wave * 16 + qd * 4;
    uint4 wlo[4], whi[4];
#pragma unroll
    for (int r = 0; r < 4; ++r) {
        const unsigned int* p = mb + (bb * 128 + tb + r) * 8;
        wlo[r] = *(const uint4*)p;
        whi[r] = *(const uint4*)(p + 4);
    }

    f32x4 rs = {0.f, 0.f, 0.f, 0.f};
#pragma unroll
    for (int nt = 0; nt < 16; ++nt) {
#pragma unroll
        for (int r = 0; r < 4; ++r) {
            unsigned int w;
            switch (nt >> 1) {
                case 0: w = wlo[r].x; break; case 1: w = wlo[r].y; break;
                case 2: w = wlo[r].z; break; case 3: w = wlo[r].w; break;
                case 4: w = whi[r].x; break; case 5: w = whi[r].y; break;
                case 6: w = whi[r].z; break; default: w = whi[r].w; break;
            }
            const bool mk = (w >> ((nt & 1) * 16 + ml)) & 1u;
            float e = mk ? __builtin_amdgcn_exp2f(sacc[nt][r]) : 0.f;
            sacc[nt][r] = e;
            rs[r] += e;
        }
    }
#pragma unroll
    for (int off = 1; off <= 8; off <<= 1) {
#pragma unroll
        for (int r = 0; r < 4; ++r) rs[r] += __shfl_xor(rs[r], off);
    }
    f32x4 pinv, pfill;
#pragma unroll
    for (int r = 0; r < 4; ++r) {
        const bool z = (rs[r] == 0.f);
        pinv[r]  = z ? 0.f : 1.f / rs[r];
        pfill[r] = z ? (1.f / 256.f) : 0.f;
    }

    short* Pw = &Ps[wave][0];
#pragma unroll
    for (int nt = 0; nt < 16; ++nt) {
        const int sgrp = 2 * nt + (ml >> 3);
        const int pos = ml & 7;
#pragma unroll
        for (int r = 0; r < 4; ++r) {
            const float p = sacc[nt][r] * pinv[r] + pfill[r];
            Pw[(sgrp * 16 + qd * 4 + r) * 8 + pos] = (short)f2bf(p);
        }
    }

    f32x4 oacc[2];
    oacc[0] = {0.f, 0.f, 0.f, 0.f};
    oacc[1] = {0.f, 0.f, 0.f, 0.f};
    const short* Vb = vbT + (size_t)i * 256 * 2048 + (size_t)b * 256;
#pragma unroll
    for (int ks = 0; ks < 8; ++ks) {
        short8 pa = *(const short8*)&Pw[((ks * 4 + qd) * 16 + ml) * 8];
#pragma unroll
        for (int n2 = 0; n2 < 2; ++n2) {
            short8 vf = *(const short8*)&Vb[(size_t)(h * HD + n2 * 16 + ml) * 2048 + ks * 32 + qd * 8];
            oacc[n2] = __builtin_amdgcn_mfma_f32_16x16x32_bf16(pa, vf, oacc[n2], 0, 0, 0);
        }
    }

#pragma unroll
    for (int n2 = 0; n2 < 2; ++n2) {
        const int d = h * HD + n2 * 16 + ml;
#pragma unroll
        for (int r = 0; r < 4; ++r) {
            const size_t idx = (bb * 128 + tb + r) * 256 + d;
            yb[idx] = (short)f2bf(oacc[n2][r] + va[idx]);
        }
    }
}

// ---------------------------------------------------------------------------
// proj2 (UNCHANGED from r5).
// ---------------------------------------------------------------------------
__global__ __launch_bounds__(256) void proj2(
    const short* __restrict__ yb, const short* __restrict__ WpT,
    const float* __restrict__ bp, float* __restrict__ out)
{
    const int bx = blockIdx.x;
    const int m0 = (bx >> 2) * 64, n0 = (bx & 3) * 64;
    const int tid = threadIdx.x;
    const int wave = tid >> 6, lane = tid & 63;
    const int wy = wave >> 1, wx = wave & 1;
    const int qd = lane >> 4, ml = lane & 15;

    f32x4 acc[2][2];
#pragma unroll
    for (int a = 0; a < 2; ++a)
#pragma unroll
        for (int b = 0; b < 2; ++b) acc[a][b] = {0.f, 0.f, 0.f, 0.f};

    for (int i = 0; i < 3; ++i) {
        const short* A = yb + (size_t)i * 1024 * 256;
        const short* W = WpT + (size_t)i * 256 * 256;
#pragma unroll
        for (int step = 0; step < 8; ++step) {
            short8 af[2], bf[2];
#pragma unroll
            for (int mt = 0; mt < 2; ++mt)
                af[mt] = *(const short8*)&A[(size_t)(m0 + wy * 32 + mt * 16 + ml) * 256 + step * 32 + qd * 8];
#pragma unroll
            for (int nt = 0; nt < 2; ++nt)
                bf[nt] = *(const short8*)&W[(size_t)(n0 + wx * 32 + nt * 16 + ml) * 256 + step * 32 + qd * 8];
#pragma unroll
            for (int mt = 0; mt < 2; ++mt)
#pragma unroll
                for (int nt = 0; nt < 2; ++nt)
                    acc[mt][nt] = __builtin_amdgcn_mfma_f32_16x16x32_bf16(
                        af[mt], bf[nt], acc[mt][nt], 0, 0, 0);
        }
    }
#pragma unroll
    for (int nt = 0; nt < 2; ++nt) {
        const int col = n0 + wx * 32 + nt * 16 + ml;
        const float b3 = bp[col] + bp[256 + col] + bp[512 + col];
#pragma unroll
        for (int mt = 0; mt < 2; ++mt) {
            const int row0 = m0 + wy * 32 + mt * 16 + qd * 4;
#pragma unroll
            for (int r = 0; r < 4; ++r)
                out[(size_t)(row0 + r) * 256 + col] = acc[mt][nt][r] + b3;
        }
    }
}

extern "C" void kernel_launch(void* const* d_in, const int* in_sizes, int n_in,
                              void* d_out, int out_size, void* d_ws, size_t ws_size,
                              hipStream_t stream)
{
    const float* x1  = (const float*)d_in[0];
    const float* x2  = (const float*)d_in[1];
    const float* ax1 = (const float*)d_in[2];
    const float* ax2 = (const float*)d_in[3];
    const int*   mk  = (const int*)d_in[4];
    const float* Wq  = (const float*)d_in[5];
    const float* bq  = (const float*)d_in[6];
    const float* Wk  = (const float*)d_in[7];
    const float* bk  = (const float*)d_in[8];
    const float* Wv  = (const float*)d_in[9];
    const float* bv  = (const float*)d_in[10];
    const float* Wp  = (const float*)d_in[11];
    const float* bp  = (const float*)d_in[12];

    char* w = (char*)d_ws;
    short* x1b   = (short*)(w + 0);              // 512 KB
    short* A2    = (short*)(w + 524288);         // 1.125 MB
    short* ax1p  = (short*)(w + 1703936);        // 64 KB
    short* WqT   = (short*)(w + 1769472);        // 384 KB
    short* WkT   = (short*)(w + 2162688);        // 432 KB
    short* WvT   = (short*)(w + 2605056);        // 432 KB
    short* WvA1T = (short*)(w + 3047424);        // 48 KB
    short* WpT   = (short*)(w + 3096576);        // 384 KB
    unsigned int* mbits = (unsigned int*)(w + 3489792);   // 96 KB
    short* qb    = (short*)(w + 3588096);        // 1.5 MB
    short* kbb   = (short*)(w + 5160960);        // 3 MB
    short* vbT   = (short*)(w + 8306688);        // 3 MB
    float* va    = (float*)(w + 11452416);       // 3 MB
    short* yb    = (short*)(w + 14598144);       // 1.5 MB

    prep_a<<<dim3(548), 256, 0, stream>>>(x1, x2, ax1, ax2, mk,
                                          x1b, A2, ax1p, mbits);
    prep_w<<<dim3(411), 256, 0, stream>>>(Wq, Wk, Wv, Wp,
                                          WqT, WkT, WvT, WvA1T, WpT);
    fused_gemm<<<dim3(288), 256, 0, stream>>>(x1b, A2, ax1p, WqT, WkT, WvT,
                                              WvA1T, bq, bk, bv, qb, kbb, vbT, va);
    attn_mfma<<<dim3(384), 256, 0, stream>>>(qb, kbb, vbT, va, mbits, yb);
    proj2<<<dim3(64), 256, 0, stream>>>(yb, WpT, bp, (float*)d_out);
}